// Round 3
// baseline (3268.287 us; speedup 1.0000x reference)
//
#include <hip/hip_runtime.h>

// ws layout (floats)
#define WS_GX   0                       // 4096: Gx[cp][c] = alpha*sum_o wk[o][c]*wq[o][cp]
#define WS_CPV  4096                    // 4096: Cpvx[c][o] = sum_m wp[o][m]*wv[m][c]
#define WS_QB   8192                    // 64:   alpha * Wk^T bq
#define WS_BPV  8256                    // 64:   Wp bv + bp
#define WS_C2   8448                    // 4096*1536 conv2 output (flattened fc input)
#define WS_Z1   (8448 + 4096*1536)      // 4096*768 fc1 output

// ---------------- K0: tiny precompute of fused weight products ----------------
__global__ void k0_precompute(const float* __restrict__ wq, const float* __restrict__ bq,
                              const float* __restrict__ wk, const float* __restrict__ bk,
                              const float* __restrict__ wv, const float* __restrict__ bv,
                              const float* __restrict__ wp, const float* __restrict__ bp,
                              float* __restrict__ ws) {
  int idx = blockIdx.x * 256 + threadIdx.x;
  const float ALPHA = 0.125f * 1.4426950408889634f;  // C^-0.5 * log2(e), folded into scores
  if (idx < 4096) {
    int cp = idx >> 6, c = idx & 63;
    float s = 0.f;
    for (int o = 0; o < 64; ++o) s += wk[o*64 + c] * wq[o*64 + cp];
    ws[WS_GX + idx] = s * ALPHA;
  } else if (idx < 8192) {
    int i = idx - 4096; int c = i >> 6, o = i & 63;
    float s = 0.f;
    for (int m = 0; m < 64; ++m) s += wp[o*64 + m] * wv[m*64 + c];
    ws[WS_CPV + i] = s;
  } else if (idx < 8256) {
    int c = idx - 8192;
    float s = 0.f;
    for (int o = 0; o < 64; ++o) s += wk[o*64 + c] * bq[o];
    ws[WS_QB + c] = s * ALPHA;
  } else if (idx < 8320) {
    int o = idx - 8256;
    float s = bp[o];
    for (int m = 0; m < 64; ++m) s += wp[o*64 + m] * bv[m];
    ws[WS_BPV + o] = s;
  }
}

// Hs swizzle: logical (c, u) -> physical index. XORing the token-block (u>>2) with the
// channel quarter (c>>4) spreads the 4 quarter-group broadcast addresses of the attention
// loop's ds_read_b128 across distinct banks (c*192 % 32 == 0 would otherwise put all
// four on the same bank = 4-way conflict). Bijective per channel since 48 % 4 == 0.
// Preserves 16B alignment for u % 4 == 0.
__device__ __forceinline__ int HsIdx(int c, int u) {
  return c*192 + ((((u >> 2) ^ (c >> 4)) << 2) | (u & 3));
}

// ---------------- K1: per-sample pipeline (conv1 -> GN -> attention -> conv2) ----------------
// block = 384 threads: 4 threads per token (16 channels each) x 2 tokens per thread.
// Thread: wave w (0..5), lane l; quarter qg = l>>4 (channel base c0 = qg*16);
// token-pair j = w*16 + (l&15); tokens t0 = j, t1 = j+96.
// Attention loop stages the thread's 16 channels of h (float4, 4 tokens of u) in REGISTERS
// once per u0-step and reuses them for both the score pass and the PV pass, for both owned
// tokens: 16 ds_read_b128 per step per thread vs 64 in the previous 1-token/2-half layout
// (4x fewer LDS instructions — prev version was jointly LDS-pipe- and VALU-bound).
// Score partials over 16 channels are combined across the 4 quarter lanes via shfl_xor 16/32.
__launch_bounds__(384, 3)
__global__ void k1_sample(const float* __restrict__ x,
                          const float* __restrict__ w1, const float* __restrict__ b1,
                          const float* __restrict__ chw, const float* __restrict__ chb,
                          const float* __restrict__ gnw, const float* __restrict__ gnb,
                          const float* __restrict__ ch2w, const float* __restrict__ ch2b,
                          const float* __restrict__ ws, float* __restrict__ c2out) {
  __shared__ __align__(16) float Hs[64 * 192];
  __shared__ float redS[384];
  __shared__ float redQ[384];
  __shared__ float scS[64];
  __shared__ float shS[64];

  const int tt   = threadIdx.x;        // 0..383
  const int b    = blockIdx.x;         // sample
  const int w    = tt >> 6;            // wave 0..5
  const int l    = tt & 63;
  const int qg   = l >> 4;             // channel quarter 0..3
  const int c0   = qg << 4;            // channel base
  const int j    = w * 16 + (l & 15);  // token-pair id 0..95
  const int t0   = j;                  // tokens owned by this thread
  const int t1   = j + 96;

  const float x0 = x[b*3+0], x1 = x[b*3+1], x2 = x[b*3+2];

  // conv1-input window for token t: hv[dy*3+dx] = h1[y+dy-1][xx+dx-1], zero-padded.
  // h1[r][cc] = x[r]*w1[cc] + b1[cc]. Recomputed on demand (cheap) instead of held live.
  auto make_hv = [&](int t, float* hv) {
    int y = t >> 6, xx = t & 63;
    #pragma unroll
    for (int dy = 0; dy < 3; ++dy) {
      int r = y + dy - 1;
      bool rv = (r >= 0) && (r < 3);
      float xr = (r == 0) ? x0 : ((r == 1) ? x1 : x2);
      #pragma unroll
      for (int dx = 0; dx < 3; ++dx) {
        int cc = xx + dx - 1;
        bool cv = (cc >= 0) && (cc < 64);
        float w1v = cv ? w1[cc] : 0.f;
        float b1v = cv ? b1[cc] : 0.f;
        hv[dy*3+dx] = rv ? fmaf(xr, w1v, b1v) : 0.f;
      }
    }
  };

  // conv1 (1->64): own 16 channels at tokens t0, t1
  {
    float hv[9];
    make_hv(t0, hv);
    #pragma unroll
    for (int i = 0; i < 16; ++i) {
      int c = c0 + i;
      float acc = chb[c];
      #pragma unroll
      for (int q = 0; q < 9; ++q) acc = fmaf(chw[c*9+q], hv[q], acc);
      Hs[HsIdx(c, t0)] = acc;
    }
    make_hv(t1, hv);
    #pragma unroll
    for (int i = 0; i < 16; ++i) {
      int c = c0 + i;
      float acc = chb[c];
      #pragma unroll
      for (int q = 0; q < 9; ++q) acc = fmaf(chw[c*9+q], hv[q], acc);
      Hs[HsIdx(c, t1)] = acc;
    }
  }
  __syncthreads();

  // instance-norm stats: thread tt handles channel c=tt&63, token segment seg=tt>>6 (32 tokens).
  // (u+c)&31 rotation keeps the 64-lane same-channel-offset pattern off a single bank.
  {
    int c = tt & 63, seg = tt >> 6;
    float s = 0.f, q = 0.f;
    for (int u = 0; u < 32; ++u) {
      float v = Hs[HsIdx(c, seg*32 + ((u + c) & 31))];
      s += v; q = fmaf(v, v, q);
    }
    redS[tt] = s; redQ[tt] = q;
  }
  __syncthreads();
  if (tt < 64) {
    float s = 0.f, q = 0.f;
    #pragma unroll
    for (int i = 0; i < 6; ++i) { s += redS[i*64 + tt]; q += redQ[i*64 + tt]; }
    float mu  = s * (1.f/192.f);
    float var = q * (1.f/192.f) - mu*mu;
    float rs  = rsqrtf(var + 1e-5f);
    float sc  = gnw[tt] * rs;
    scS[tt] = sc;
    shS[tt] = gnb[tt] - mu * sc;
  }
  __syncthreads();
  // normalize in place (own 16 channels at t0, t1)
  #pragma unroll
  for (int i = 0; i < 16; ++i) {
    int c = c0 + i;
    int i0 = HsIdx(c, t0), i1 = HsIdx(c, t1);
    Hs[i0] = fmaf(Hs[i0], scS[c], shS[c]);
    Hs[i1] = fmaf(Hs[i1], scS[c], shS[c]);
  }
  __syncthreads();

  // ---- attention ----
  const float* __restrict__ Gx  = ws + WS_GX;
  const float* __restrict__ qb  = ws + WS_QB;
  const float* __restrict__ Cpv = ws + WS_CPV;
  const float* __restrict__ bpv = ws + WS_BPV;

  // q~[c] for own 16 channels, both tokens: qt = qb + sum_cp Gx[cp][c] * h[cp][t]
  float qtA[16], qtB[16];
  #pragma unroll
  for (int i = 0; i < 16; ++i) { qtA[i] = qb[c0 + i]; qtB[i] = qtA[i]; }
  for (int cp = 0; cp < 64; ++cp) {
    float hA = Hs[HsIdx(cp, t0)];
    float hB = Hs[HsIdx(cp, t1)];
    const float* g = Gx + cp*64 + c0;
    #pragma unroll
    for (int i = 0; i < 16; ++i) {
      qtA[i] = fmaf(g[i], hA, qtA[i]);
      qtB[i] = fmaf(g[i], hB, qtB[i]);
    }
  }

  // online softmax + g = attn @ h, staged h4 reused for score AND PV, both tokens.
  float gA[16], gB[16];
  #pragma unroll
  for (int i = 0; i < 16; ++i) { gA[i] = 0.f; gB[i] = 0.f; }
  float mA = -1e30f, lA = 0.f, mB = -1e30f, lB = 0.f;
  for (int u0 = 0; u0 < 192; u0 += 4) {
    const int xb = ((u0 >> 2) ^ qg) << 2;   // swizzled token-block offset (same for all own c)
    float4 h4[16];
    #pragma unroll
    for (int i = 0; i < 16; ++i) h4[i] = *(const float4*)&Hs[(c0 + i)*192 + xb];

    float sA0 = 0.f, sA1 = 0.f, sA2 = 0.f, sA3 = 0.f;
    float sB0 = 0.f, sB1 = 0.f, sB2 = 0.f, sB3 = 0.f;
    #pragma unroll
    for (int i = 0; i < 16; ++i) {
      float4 h = h4[i];
      float qa = qtA[i], qbv = qtB[i];
      sA0 = fmaf(qa, h.x, sA0); sA1 = fmaf(qa, h.y, sA1);
      sA2 = fmaf(qa, h.z, sA2); sA3 = fmaf(qa, h.w, sA3);
      sB0 = fmaf(qbv, h.x, sB0); sB1 = fmaf(qbv, h.y, sB1);
      sB2 = fmaf(qbv, h.z, sB2); sB3 = fmaf(qbv, h.w, sB3);
    }
    // combine channel quarters across lanes l^16, l^32
    sA0 += __shfl_xor(sA0, 16); sA0 += __shfl_xor(sA0, 32);
    sA1 += __shfl_xor(sA1, 16); sA1 += __shfl_xor(sA1, 32);
    sA2 += __shfl_xor(sA2, 16); sA2 += __shfl_xor(sA2, 32);
    sA3 += __shfl_xor(sA3, 16); sA3 += __shfl_xor(sA3, 32);
    sB0 += __shfl_xor(sB0, 16); sB0 += __shfl_xor(sB0, 32);
    sB1 += __shfl_xor(sB1, 16); sB1 += __shfl_xor(sB1, 32);
    sB2 += __shfl_xor(sB2, 16); sB2 += __shfl_xor(sB2, 32);
    sB3 += __shfl_xor(sB3, 16); sB3 += __shfl_xor(sB3, 32);

    float mnA = fmaxf(fmaxf(fmaxf(sA0, sA1), fmaxf(sA2, sA3)), mA);
    float aA  = __builtin_exp2f(mA - mnA);
    float pA0 = __builtin_exp2f(sA0 - mnA);
    float pA1 = __builtin_exp2f(sA1 - mnA);
    float pA2 = __builtin_exp2f(sA2 - mnA);
    float pA3 = __builtin_exp2f(sA3 - mnA);
    lA = fmaf(lA, aA, (pA0 + pA1) + (pA2 + pA3));
    mA = mnA;

    float mnB = fmaxf(fmaxf(fmaxf(sB0, sB1), fmaxf(sB2, sB3)), mB);
    float aB  = __builtin_exp2f(mB - mnB);
    float pB0 = __builtin_exp2f(sB0 - mnB);
    float pB1 = __builtin_exp2f(sB1 - mnB);
    float pB2 = __builtin_exp2f(sB2 - mnB);
    float pB3 = __builtin_exp2f(sB3 - mnB);
    lB = fmaf(lB, aB, (pB0 + pB1) + (pB2 + pB3));
    mB = mnB;

    #pragma unroll
    for (int i = 0; i < 16; ++i) {
      float4 h = h4[i];
      float ga = gA[i] * aA;
      ga = fmaf(pA0, h.x, ga); ga = fmaf(pA1, h.y, ga);
      ga = fmaf(pA2, h.z, ga); ga = fmaf(pA3, h.w, ga);
      gA[i] = ga;
      float gb = gB[i] * aB;
      gb = fmaf(pB0, h.x, gb); gb = fmaf(pB1, h.y, gb);
      gb = fmaf(pB2, h.z, gb); gb = fmaf(pB3, h.w, gb);
      gB[i] = gb;
    }
  }
  {
    float rlA = 1.f / lA, rlB = 1.f / lB;
    #pragma unroll
    for (int i = 0; i < 16; ++i) { gA[i] *= rlA; gB[i] *= rlB; }
  }

  // Hs (normalized h) is dead now — park g[c][t] there for the p-projection.
  __syncthreads();   // all attention reads of Hs complete before overwrite
  #pragma unroll
  for (int i = 0; i < 16; ++i) {
    Hs[HsIdx(c0 + i, t0)] = gA[i];
    Hs[HsIdx(c0 + i, t1)] = gB[i];
  }
  __syncthreads();

  // p[o] = bpv[o] + sum_c Cpvx[c][o]*g[c]  (own 16 outputs, all 64 c; reuse qt regs)
  #pragma unroll
  for (int i = 0; i < 16; ++i) { qtA[i] = bpv[c0 + i]; qtB[i] = qtA[i]; }
  for (int c = 0; c < 64; ++c) {
    float ga = Hs[HsIdx(c, t0)];
    float gb = Hs[HsIdx(c, t1)];
    const float* cp = Cpv + c*64 + c0;
    #pragma unroll
    for (int i = 0; i < 16; ++i) {
      qtA[i] = fmaf(cp[i], ga, qtA[i]);
      qtB[i] = fmaf(cp[i], gb, qtB[i]);
    }
  }
  __syncthreads();   // all g reads complete before overwrite

  // residual: res[c][t] = conv1(c,t) (recomputed) + p[c]
  {
    float hv[9];
    make_hv(t0, hv);
    #pragma unroll
    for (int i = 0; i < 16; ++i) {
      int c = c0 + i;
      float acc = chb[c];
      #pragma unroll
      for (int q = 0; q < 9; ++q) acc = fmaf(chw[c*9+q], hv[q], acc);
      Hs[HsIdx(c, t0)] = acc + qtA[i];
    }
    make_hv(t1, hv);
    #pragma unroll
    for (int i = 0; i < 16; ++i) {
      int c = c0 + i;
      float acc = chb[c];
      #pragma unroll
      for (int q = 0; q < 9; ++q) acc = fmaf(chw[c*9+q], hv[q], acc);
      Hs[HsIdx(c, t1)] = acc + qtB[i];
    }
  }
  __syncthreads();

  // conv2 (64->8): partial over own 16 input channels, combined across the 4 quarter lanes.
  float acc2A[8], acc2B[8];
  #pragma unroll
  for (int o = 0; o < 8; ++o) {
    acc2A[o] = (qg == 0) ? ch2b[o] : 0.f;
    acc2B[o] = (qg == 0) ? ch2b[o] : 0.f;
  }
  {
    const int y0 = t0 >> 6, xx0 = t0 & 63;
    const int y1 = t1 >> 6, xx1 = t1 & 63;
    for (int i = 0; i < 16; ++i) {
      int c = c0 + i;
      float win[9];
      #pragma unroll
      for (int dy = 0; dy < 3; ++dy) {
        int r = y0 + dy - 1;
        bool rv = (r >= 0) && (r < 3);
        #pragma unroll
        for (int dx = 0; dx < 3; ++dx) {
          int cc = xx0 + dx - 1;
          bool cv = (cc >= 0) && (cc < 64);
          win[dy*3+dx] = (rv && cv) ? Hs[HsIdx(c, r*64 + cc)] : 0.f;
        }
      }
      #pragma unroll
      for (int o = 0; o < 8; ++o) {
        const float* wrow = ch2w + o*576 + c*9;
        float a = acc2A[o];
        #pragma unroll
        for (int q = 0; q < 9; ++q) a = fmaf(wrow[q], win[q], a);
        acc2A[o] = a;
      }
      #pragma unroll
      for (int dy = 0; dy < 3; ++dy) {
        int r = y1 + dy - 1;
        bool rv = (r >= 0) && (r < 3);
        #pragma unroll
        for (int dx = 0; dx < 3; ++dx) {
          int cc = xx1 + dx - 1;
          bool cv = (cc >= 0) && (cc < 64);
          win[dy*3+dx] = (rv && cv) ? Hs[HsIdx(c, r*64 + cc)] : 0.f;
        }
      }
      #pragma unroll
      for (int o = 0; o < 8; ++o) {
        const float* wrow = ch2w + o*576 + c*9;
        float a = acc2B[o];
        #pragma unroll
        for (int q = 0; q < 9; ++q) a = fmaf(wrow[q], win[q], a);
        acc2B[o] = a;
      }
    }
  }
  #pragma unroll
  for (int o = 0; o < 8; ++o) {
    acc2A[o] += __shfl_xor(acc2A[o], 16); acc2A[o] += __shfl_xor(acc2A[o], 32);
    acc2B[o] += __shfl_xor(acc2B[o], 16); acc2B[o] += __shfl_xor(acc2B[o], 32);
  }
  if (qg == 0) {
    #pragma unroll
    for (int o = 0; o < 8; ++o) {
      c2out[b*1536 + o*192 + t0] = acc2A[o];
      c2out[b*1536 + o*192 + t1] = acc2B[o];
    }
  }
}

// ---------------- K2: fc1 GEMM  z1[4096][768] = relu(c2[4096][1536] @ w2^T + b2) ----------------
// 256 threads, tile 128m x 64n x 32k, 8x4 per thread (rows strided by 16 for bank-conflict-free reads)
__launch_bounds__(256, 4)
__global__ void k2_fc1(const float* __restrict__ A, const float* __restrict__ w2,
                       const float* __restrict__ b2, float* __restrict__ z1) {
  __shared__ float As[128 * 33];
  __shared__ float Bs[32 * 68];
  const int tid = threadIdx.x;
  const int m0 = blockIdx.x * 128;
  const int n0 = blockIdx.y * 64;
  const int tm = tid & 15, tn = tid >> 4;   // tn 0..15

  float acc[8][4];
  #pragma unroll
  for (int i = 0; i < 8; ++i)
    #pragma unroll
    for (int j = 0; j < 4; ++j) acc[i][j] = 0.f;

  for (int k0 = 0; k0 < 1536; k0 += 32) {
    #pragma unroll
    for (int i = 0; i < 4; ++i) {   // stage A 128x32
      int j = tid + i*256;
      int mm = j >> 3, k4 = (j & 7) << 2;
      float4 v = *(const float4*)&A[(m0+mm)*1536 + k0 + k4];
      As[mm*33 + k4+0] = v.x; As[mm*33 + k4+1] = v.y;
      As[mm*33 + k4+2] = v.z; As[mm*33 + k4+3] = v.w;
    }
    #pragma unroll
    for (int i = 0; i < 2; ++i) {   // stage B 64x32 transposed -> Bs[k][68]
      int j = tid + i*256;
      int nn = j >> 3, k4 = (j & 7) << 2;
      float4 v = *(const float4*)&w2[(n0+nn)*1536 + k0 + k4];
      Bs[(k4+0)*68 + nn] = v.x; Bs[(k4+1)*68 + nn] = v.y;
      Bs[(k4+2)*68 + nn] = v.z; Bs[(k4+3)*68 + nn] = v.w;
    }
    __syncthreads();
    #pragma unroll
    for (int k = 0; k < 32; ++k) {
      float a[8];
      #pragma unroll
      for (int i = 0; i < 8; ++i) a[i] = As[(tm + 16*i)*33 + k];
      float4 bv = *(const float4*)&Bs[k*68 + tn*4];
      #pragma unroll
      for (int i = 0; i < 8; ++i) {
        acc[i][0] = fmaf(a[i], bv.x, acc[i][0]);
        acc[i][1] = fmaf(a[i], bv.y, acc[i][1]);
        acc[i][2] = fmaf(a[i], bv.z, acc[i][2]);
        acc[i][3] = fmaf(a[i], bv.w, acc[i][3]);
      }
    }
    __syncthreads();
  }
  float4 bb = *(const float4*)&b2[n0 + tn*4];
  #pragma unroll
  for (int i = 0; i < 8; ++i) {
    float4 r;
    r.x = fmaxf(acc[i][0] + bb.x, 0.f);
    r.y = fmaxf(acc[i][1] + bb.y, 0.f);
    r.z = fmaxf(acc[i][2] + bb.z, 0.f);
    r.w = fmaxf(acc[i][3] + bb.w, 0.f);
    *(float4*)&z1[(m0 + tm + 16*i)*768 + n0 + tn*4] = r;
  }
}

// ---------------- K3: fc2+relu+fc3  out[b] = b4 + sum_o w4[o]*relu(b3[o] + w3[o].z1[b]) ----------------
// 16 samples per block, 256 blocks
__launch_bounds__(256, 2)
__global__ void k3_fc23(const float* __restrict__ z1, const float* __restrict__ w3,
                        const float* __restrict__ b3, const float* __restrict__ w4,
                        const float* __restrict__ b4, float* __restrict__ out) {
  __shared__ float Zs[16 * 772];
  __shared__ float Ws[32 * 68];
  __shared__ float red[256];
  const int tid = threadIdx.x;
  const int m0 = blockIdx.x * 16;
  const int tm = tid & 15, tn = tid >> 4;   // tn 0..15 -> 4 fc2 outputs each

  #pragma unroll
  for (int i = 0; i < 12; ++i) {   // stage Zs 16x768
    int j = tid + i*256;
    int mm = j / 192;
    int kq = j - mm*192;
    float4 v = *(const float4*)&z1[(m0+mm)*768 + kq*4];
    *(float4*)&Zs[mm*772 + kq*4] = v;
  }

  float a0 = 0.f, a1 = 0.f, a2 = 0.f, a3 = 0.f;
  for (int k0 = 0; k0 < 768; k0 += 32) {
    __syncthreads();
    #pragma unroll
    for (int i = 0; i < 2; ++i) {  // stage Ws[32k][68] transposed from w3[n][k]
      int j = tid + i*256;
      int nn = j >> 3, k4 = (j & 7) << 2;
      float4 v = *(const float4*)&w3[nn*768 + k0 + k4];
      Ws[(k4+0)*68 + nn] = v.x; Ws[(k4+1)*68 + nn] = v.y;
      Ws[(k4+2)*68 + nn] = v.z; Ws[(k4+3)*68 + nn] = v.w;
    }
    __syncthreads();
    #pragma unroll
    for (int k = 0; k < 32; k += 4) {
      float4 z  = *(const float4*)&Zs[tm*772 + k0 + k];
      float4 w0 = *(const float4*)&Ws[(k+0)*68 + tn*4];
      float4 w1v= *(const float4*)&Ws[(k+1)*68 + tn*4];
      float4 w2v= *(const float4*)&Ws[(k+2)*68 + tn*4];
      float4 w3v= *(const float4*)&Ws[(k+3)*68 + tn*4];
      a0 = fmaf(z.x, w0.x, a0); a1 = fmaf(z.x, w0.y, a1); a2 = fmaf(z.x, w0.z, a2); a3 = fmaf(z.x, w0.w, a3);
      a0 = fmaf(z.y, w1v.x, a0); a1 = fmaf(z.y, w1v.y, a1); a2 = fmaf(z.y, w1v.z, a2); a3 = fmaf(z.y, w1v.w, a3);
      a0 = fmaf(z.z, w2v.x, a0); a1 = fmaf(z.z, w2v.y, a1); a2 = fmaf(z.z, w2v.z, a2); a3 = fmaf(z.z, w2v.w, a3);
      a0 = fmaf(z.w, w3v.x, a0); a1 = fmaf(z.w, w3v.y, a1); a2 = fmaf(z.w, w3v.z, a2); a3 = fmaf(z.w, w3v.w, a3);
    }
  }
  float4 b3v = *(const float4*)&b3[tn*4];
  float4 w4v = *(const float4*)&w4[tn*4];
  float p = fmaxf(a0 + b3v.x, 0.f) * w4v.x
          + fmaxf(a1 + b3v.y, 0.f) * w4v.y
          + fmaxf(a2 + b3v.z, 0.f) * w4v.z
          + fmaxf(a3 + b3v.w, 0.f) * w4v.w;
  red[tid] = p;
  __syncthreads();
  if (tid < 16) {
    float s = 0.f;
    #pragma unroll
    for (int i = 0; i < 16; ++i) s += red[i*16 + tid];
    out[m0 + tid] = s + b4[0];
  }
}

extern "C" void kernel_launch(void* const* d_in, const int* in_sizes, int n_in,
                              void* d_out, int out_size, void* d_ws, size_t ws_size,
                              hipStream_t stream) {
  const float* x    = (const float*)d_in[0];
  const float* w1   = (const float*)d_in[1];
  const float* b1   = (const float*)d_in[2];
  const float* chw  = (const float*)d_in[3];
  const float* chb  = (const float*)d_in[4];
  const float* gnw  = (const float*)d_in[5];
  const float* gnb  = (const float*)d_in[6];
  const float* wq   = (const float*)d_in[7];
  const float* bq   = (const float*)d_in[8];
  const float* wk   = (const float*)d_in[9];
  const float* bk   = (const float*)d_in[10];
  const float* wv   = (const float*)d_in[11];
  const float* bv   = (const float*)d_in[12];
  const float* wp   = (const float*)d_in[13];
  const float* bp   = (const float*)d_in[14];
  const float* ch2w = (const float*)d_in[15];
  const float* ch2b = (const float*)d_in[16];
  const float* w2   = (const float*)d_in[17];
  const float* b2   = (const float*)d_in[18];
  const float* w3   = (const float*)d_in[19];
  const float* b3   = (const float*)d_in[20];
  const float* w4   = (const float*)d_in[21];
  const float* b4   = (const float*)d_in[22];
  (void)bk; (void)in_sizes; (void)n_in; (void)out_size; (void)ws_size;

  float* ws = (float*)d_ws;
  float* c2 = ws + WS_C2;
  float* z1 = ws + WS_Z1;
  float* out = (float*)d_out;

  hipLaunchKernelGGL(k0_precompute, dim3(34), dim3(256), 0, stream,
                     wq, bq, wk, bk, wv, bv, wp, bp, ws);
  hipLaunchKernelGGL(k1_sample, dim3(4096), dim3(384), 0, stream,
                     x, w1, b1, chw, chb, gnw, gnb, ch2w, ch2b, ws, c2);
  hipLaunchKernelGGL(k2_fc1, dim3(32, 12), dim3(256), 0, stream, c2, w2, b2, z1);
  hipLaunchKernelGGL(k3_fc23, dim3(256), dim3(256), 0, stream, z1, w3, b3, w4, b4, out);
}

// Round 4
// 2451.892 us; speedup vs baseline: 1.3330x; 1.3330x over previous
//
#include <hip/hip_runtime.h>

// ws layout (floats)
#define WS_GX   0                       // 4096: Gx[cp][c] = alpha*sum_o wk[o][c]*wq[o][cp]
#define WS_CPV  4096                    // 4096: Cpvx[c][o] = sum_m wp[o][m]*wv[m][c]
#define WS_QB   8192                    // 64:   alpha * Wk^T bq
#define WS_BPV  8256                    // 64:   Wp bv + bp
#define WS_C2   8448                    // 4096*1536 conv2 output (flattened fc input)
#define WS_Z1   (8448 + 4096*1536)      // 4096*768 fc1 output

// ---------------- K0: tiny precompute of fused weight products ----------------
__global__ void k0_precompute(const float* __restrict__ wq, const float* __restrict__ bq,
                              const float* __restrict__ wk, const float* __restrict__ bk,
                              const float* __restrict__ wv, const float* __restrict__ bv,
                              const float* __restrict__ wp, const float* __restrict__ bp,
                              float* __restrict__ ws) {
  int idx = blockIdx.x * 256 + threadIdx.x;
  const float ALPHA = 0.125f * 1.4426950408889634f;  // C^-0.5 * log2(e), folded into scores
  if (idx < 4096) {
    int cp = idx >> 6, c = idx & 63;
    float s = 0.f;
    for (int o = 0; o < 64; ++o) s += wk[o*64 + c] * wq[o*64 + cp];
    ws[WS_GX + idx] = s * ALPHA;
  } else if (idx < 8192) {
    int i = idx - 4096; int c = i >> 6, o = i & 63;
    float s = 0.f;
    for (int m = 0; m < 64; ++m) s += wp[o*64 + m] * wv[m*64 + c];
    ws[WS_CPV + i] = s;
  } else if (idx < 8256) {
    int c = idx - 8192;
    float s = 0.f;
    for (int o = 0; o < 64; ++o) s += wk[o*64 + c] * bq[o];
    ws[WS_QB + c] = s * ALPHA;
  } else if (idx < 8320) {
    int o = idx - 8256;
    float s = bp[o];
    for (int m = 0; m < 64; ++m) s += wp[o*64 + m] * bv[m];
    ws[WS_BPV + o] = s;
  }
}

// Hs swizzle: logical (c,u) -> physical slot c*192 + (u&~31) | ((u&31) ^ ((c>>4)<<3)).
// XOR of the low-5 token bits by channel-quarter*8:
//  - attention broadcast ds_read_b128 (4 quarter-groups, same u0): the 4 groups' bases
//    differ by XOR {0,8,16,24} -> disjoint 4-bank sets -> conflict-free (was 4-way);
//  - all scalar phases (b32, 16 consecutive tokens per group): groups cover 16-bank
//    halves pairwise -> exactly 2-way, which is free on CDNA4 (m136).
// Preserves low-2 token bits -> float4 contiguity and 16B alignment kept.
// (Round-3's token-block XOR fixed the reads but made every scalar write 4-way ->
//  2.0e7 bank conflicts; this variant fixes both sides.)

// ---------------- K1: per-sample pipeline (conv1 -> GN -> attention -> conv2) ----------------
// block = 384 threads: 4 threads per token (16 channels each) x 2 tokens per thread.
// Thread: wave w (0..5), lane l; quarter qg = l>>4 (channels c0 = qg*16);
// token-pair j = w*16 + (l&15); tokens t0 = j, t1 = j+96.
// vs round-2 (2 threads/token, 32ch): halves wave-level LDS instructions in the attention
// loop (32 ds_read_b128 per step vs 64) and halves per-token VALU, WITHOUT the round-3
// h4[16] register staging that spilled to scratch (585 MB write traffic). PV re-reads h.
// Score partials combined across the 4 quarter lanes via shfl_xor 16/32.
__launch_bounds__(384, 4)
__global__ void k1_sample(const float* __restrict__ x,
                          const float* __restrict__ w1, const float* __restrict__ b1,
                          const float* __restrict__ chw, const float* __restrict__ chb,
                          const float* __restrict__ gnw, const float* __restrict__ gnb,
                          const float* __restrict__ ch2w, const float* __restrict__ ch2b,
                          const float* __restrict__ ws, float* __restrict__ c2out) {
  __shared__ __align__(16) float Hs[64 * 192];
  __shared__ float redS[384];
  __shared__ float redQ[384];
  __shared__ float scS[64];
  __shared__ float shS[64];

  const int tt   = threadIdx.x;        // 0..383
  const int b    = blockIdx.x;         // sample
  const int w    = tt >> 6;            // wave 0..5
  const int l    = tt & 63;
  const int qg   = l >> 4;             // channel quarter 0..3
  const int c0   = qg << 4;            // channel base
  const int rot  = qg << 3;            // bank-swizzle rotation for own channels
  const int j    = w * 16 + (l & 15);  // token-pair id 0..95
  const int t0   = j;                  // tokens owned by this thread
  const int t1   = j + 96;
  // physical slots of own tokens under own channels' swizzle
  const int p0   = (t0 & ~31) | ((t0 & 31) ^ rot);
  const int p1   = (t1 & ~31) | ((t1 & 31) ^ rot);

  const float x0 = x[b*3+0], x1 = x[b*3+1], x2 = x[b*3+2];

  // conv1-input window for token t: hv[dy*3+dx] = h1[y+dy-1][xx+dx-1], zero-padded.
  // h1[r][cc] = x[r]*w1[cc] + b1[cc]. Recomputed on demand (cheap) instead of held live.
  auto make_hv = [&](int t, float* hv) {
    int y = t >> 6, xx = t & 63;
    #pragma unroll
    for (int dy = 0; dy < 3; ++dy) {
      int r = y + dy - 1;
      bool rv = (r >= 0) && (r < 3);
      float xr = (r == 0) ? x0 : ((r == 1) ? x1 : x2);
      #pragma unroll
      for (int dx = 0; dx < 3; ++dx) {
        int cc = xx + dx - 1;
        bool cv = (cc >= 0) && (cc < 64);
        float w1v = cv ? w1[cc] : 0.f;
        float b1v = cv ? b1[cc] : 0.f;
        hv[dy*3+dx] = rv ? fmaf(xr, w1v, b1v) : 0.f;
      }
    }
  };

  // conv1 (1->64): own 16 channels at tokens t0, t1
  {
    float hv[9];
    make_hv(t0, hv);
    #pragma unroll
    for (int i = 0; i < 16; ++i) {
      int c = c0 + i;
      float acc = chb[c];
      #pragma unroll
      for (int q = 0; q < 9; ++q) acc = fmaf(chw[c*9+q], hv[q], acc);
      Hs[c*192 + p0] = acc;
    }
    make_hv(t1, hv);
    #pragma unroll
    for (int i = 0; i < 16; ++i) {
      int c = c0 + i;
      float acc = chb[c];
      #pragma unroll
      for (int q = 0; q < 9; ++q) acc = fmaf(chw[c*9+q], hv[q], acc);
      Hs[c*192 + p1] = acc;
    }
  }
  __syncthreads();

  // instance-norm stats: thread tt handles channel c=tt&63, token segment seg=tt>>6.
  // (u+c)&31 rotation + swizzle -> 2-way max (free).
  {
    int c = tt & 63, seg = tt >> 6;
    int rc = (c >> 4) << 3;
    int base = c*192 + seg*32;
    float s = 0.f, q = 0.f;
    for (int u = 0; u < 32; ++u) {
      float v = Hs[base + (((u + c) & 31) ^ rc)];
      s += v; q = fmaf(v, v, q);
    }
    redS[tt] = s; redQ[tt] = q;
  }
  __syncthreads();
  if (tt < 64) {
    float s = 0.f, q = 0.f;
    #pragma unroll
    for (int i = 0; i < 6; ++i) { s += redS[i*64 + tt]; q += redQ[i*64 + tt]; }
    float mu  = s * (1.f/192.f);
    float var = q * (1.f/192.f) - mu*mu;
    float rs  = rsqrtf(var + 1e-5f);
    float sc  = gnw[tt] * rs;
    scS[tt] = sc;
    shS[tt] = gnb[tt] - mu * sc;
  }
  __syncthreads();
  // normalize in place (own 16 channels at t0, t1)
  #pragma unroll
  for (int i = 0; i < 16; ++i) {
    int c = c0 + i;
    float sc = scS[c], sh = shS[c];
    Hs[c*192 + p0] = fmaf(Hs[c*192 + p0], sc, sh);
    Hs[c*192 + p1] = fmaf(Hs[c*192 + p1], sc, sh);
  }
  __syncthreads();

  // ---- attention ----
  const float* __restrict__ Gx  = ws + WS_GX;
  const float* __restrict__ qb  = ws + WS_QB;
  const float* __restrict__ Cpv = ws + WS_CPV;
  const float* __restrict__ bpv = ws + WS_BPV;

  // q~[c] for own 16 channels, both tokens: qt = qb + sum_cp Gx[cp][c] * h[cp][t].
  // cp iterated in 4 quarter-groups so the swizzled slot of t0/t1 is hoisted per group.
  float qtA[16], qtB[16];
  #pragma unroll
  for (int i = 0; i < 16; ++i) { qtA[i] = qb[c0 + i]; qtB[i] = qtA[i]; }
  for (int g = 0; g < 4; ++g) {
    const int rg  = g << 3;
    const int s0i = (t0 & ~31) | ((t0 & 31) ^ rg);
    const int s1i = (t1 & ~31) | ((t1 & 31) ^ rg);
    for (int cp = g*16; cp < g*16 + 16; ++cp) {
      float hA = Hs[cp*192 + s0i];
      float hB = Hs[cp*192 + s1i];
      const float* gx = Gx + cp*64 + c0;
      #pragma unroll
      for (int i = 0; i < 16; ++i) {
        qtA[i] = fmaf(gx[i], hA, qtA[i]);
        qtB[i] = fmaf(gx[i], hB, qtB[i]);
      }
    }
  }

  // online softmax + g = attn @ h for both tokens. h read twice per step (score + PV)
  // — 32 ds_read_b128 per step per thread, no register staging (no spill).
  float gA[16], gB[16];
  #pragma unroll
  for (int i = 0; i < 16; ++i) { gA[i] = 0.f; gB[i] = 0.f; }
  float mA = -1e30f, lA = 0.f, mB = -1e30f, lB = 0.f;
  for (int u0 = 0; u0 < 192; u0 += 4) {
    const int up = (u0 & ~31) | ((u0 & 31) ^ rot);   // physical base of logical u0..u0+3

    float sA0 = 0.f, sA1 = 0.f, sA2 = 0.f, sA3 = 0.f;
    float sB0 = 0.f, sB1 = 0.f, sB2 = 0.f, sB3 = 0.f;
    #pragma unroll
    for (int i = 0; i < 16; ++i) {
      const float4 h = *(const float4*)&Hs[(c0 + i)*192 + up];
      float qa = qtA[i], qbv = qtB[i];
      sA0 = fmaf(qa, h.x, sA0); sA1 = fmaf(qa, h.y, sA1);
      sA2 = fmaf(qa, h.z, sA2); sA3 = fmaf(qa, h.w, sA3);
      sB0 = fmaf(qbv, h.x, sB0); sB1 = fmaf(qbv, h.y, sB1);
      sB2 = fmaf(qbv, h.z, sB2); sB3 = fmaf(qbv, h.w, sB3);
    }
    // combine channel quarters across lanes l^16, l^32
    sA0 += __shfl_xor(sA0, 16); sA0 += __shfl_xor(sA0, 32);
    sA1 += __shfl_xor(sA1, 16); sA1 += __shfl_xor(sA1, 32);
    sA2 += __shfl_xor(sA2, 16); sA2 += __shfl_xor(sA2, 32);
    sA3 += __shfl_xor(sA3, 16); sA3 += __shfl_xor(sA3, 32);
    sB0 += __shfl_xor(sB0, 16); sB0 += __shfl_xor(sB0, 32);
    sB1 += __shfl_xor(sB1, 16); sB1 += __shfl_xor(sB1, 32);
    sB2 += __shfl_xor(sB2, 16); sB2 += __shfl_xor(sB2, 32);
    sB3 += __shfl_xor(sB3, 16); sB3 += __shfl_xor(sB3, 32);

    float mnA = fmaxf(fmaxf(fmaxf(sA0, sA1), fmaxf(sA2, sA3)), mA);
    float aA  = __builtin_exp2f(mA - mnA);
    float pA0 = __builtin_exp2f(sA0 - mnA);
    float pA1 = __builtin_exp2f(sA1 - mnA);
    float pA2 = __builtin_exp2f(sA2 - mnA);
    float pA3 = __builtin_exp2f(sA3 - mnA);
    lA = fmaf(lA, aA, (pA0 + pA1) + (pA2 + pA3));
    mA = mnA;

    float mnB = fmaxf(fmaxf(fmaxf(sB0, sB1), fmaxf(sB2, sB3)), mB);
    float aB  = __builtin_exp2f(mB - mnB);
    float pB0 = __builtin_exp2f(sB0 - mnB);
    float pB1 = __builtin_exp2f(sB1 - mnB);
    float pB2 = __builtin_exp2f(sB2 - mnB);
    float pB3 = __builtin_exp2f(sB3 - mnB);
    lB = fmaf(lB, aB, (pB0 + pB1) + (pB2 + pB3));
    mB = mnB;

    #pragma unroll
    for (int i = 0; i < 16; ++i) {
      const float4 h = *(const float4*)&Hs[(c0 + i)*192 + up];
      float ga = gA[i] * aA;
      ga = fmaf(pA0, h.x, ga); ga = fmaf(pA1, h.y, ga);
      ga = fmaf(pA2, h.z, ga); ga = fmaf(pA3, h.w, ga);
      gA[i] = ga;
      float gb = gB[i] * aB;
      gb = fmaf(pB0, h.x, gb); gb = fmaf(pB1, h.y, gb);
      gb = fmaf(pB2, h.z, gb); gb = fmaf(pB3, h.w, gb);
      gB[i] = gb;
    }
  }
  {
    float rlA = 1.f / lA, rlB = 1.f / lB;
    #pragma unroll
    for (int i = 0; i < 16; ++i) { gA[i] *= rlA; gB[i] *= rlB; }
  }

  // Hs (normalized h) is dead now — park g[c][t] there for the p-projection.
  __syncthreads();   // all attention reads of Hs complete before overwrite
  #pragma unroll
  for (int i = 0; i < 16; ++i) {
    Hs[(c0 + i)*192 + p0] = gA[i];
    Hs[(c0 + i)*192 + p1] = gB[i];
  }
  __syncthreads();

  // p[o] = bpv[o] + sum_c Cpvx[c][o]*g[c]  (own 16 outputs, all 64 c; reuse qt regs)
  #pragma unroll
  for (int i = 0; i < 16; ++i) { qtA[i] = bpv[c0 + i]; qtB[i] = qtA[i]; }
  for (int g = 0; g < 4; ++g) {
    const int rg  = g << 3;
    const int s0i = (t0 & ~31) | ((t0 & 31) ^ rg);
    const int s1i = (t1 & ~31) | ((t1 & 31) ^ rg);
    for (int c = g*16; c < g*16 + 16; ++c) {
      float ga = Hs[c*192 + s0i];
      float gb = Hs[c*192 + s1i];
      const float* cp = Cpv + c*64 + c0;
      #pragma unroll
      for (int i = 0; i < 16; ++i) {
        qtA[i] = fmaf(cp[i], ga, qtA[i]);
        qtB[i] = fmaf(cp[i], gb, qtB[i]);
      }
    }
  }
  __syncthreads();   // all g reads complete before overwrite

  // residual: res[c][t] = conv1(c,t) (recomputed) + p[c]
  {
    float hv[9];
    make_hv(t0, hv);
    #pragma unroll
    for (int i = 0; i < 16; ++i) {
      int c = c0 + i;
      float acc = chb[c];
      #pragma unroll
      for (int q = 0; q < 9; ++q) acc = fmaf(chw[c*9+q], hv[q], acc);
      Hs[c*192 + p0] = acc + qtA[i];
    }
    make_hv(t1, hv);
    #pragma unroll
    for (int i = 0; i < 16; ++i) {
      int c = c0 + i;
      float acc = chb[c];
      #pragma unroll
      for (int q = 0; q < 9; ++q) acc = fmaf(chw[c*9+q], hv[q], acc);
      Hs[c*192 + p1] = acc + qtB[i];
    }
  }
  __syncthreads();

  // conv2 (64->8): partial over own 16 input channels, combined across the 4 quarter lanes.
  // Window reads use the swizzle inline (rot is the own-channel rotation, hoisted).
  float acc2A[8], acc2B[8];
  #pragma unroll
  for (int o = 0; o < 8; ++o) {
    acc2A[o] = (qg == 0) ? ch2b[o] : 0.f;
    acc2B[o] = (qg == 0) ? ch2b[o] : 0.f;
  }
  {
    const int y0 = t0 >> 6, xx0 = t0 & 63;
    const int y1 = t1 >> 6, xx1 = t1 & 63;
    for (int i = 0; i < 16; ++i) {
      int c = c0 + i;
      const int cb = c*192;
      float win[9];
      #pragma unroll
      for (int dy = 0; dy < 3; ++dy) {
        int r = y0 + dy - 1;
        bool rv = (r >= 0) && (r < 3);
        #pragma unroll
        for (int dx = 0; dx < 3; ++dx) {
          int cc = xx0 + dx - 1;
          bool cv = (cc >= 0) && (cc < 64);
          int tok = r*64 + cc;
          int ph  = (tok & ~31) | ((tok & 31) ^ rot);
          win[dy*3+dx] = (rv && cv) ? Hs[cb + ph] : 0.f;
        }
      }
      #pragma unroll
      for (int o = 0; o < 8; ++o) {
        const float* wrow = ch2w + o*576 + c*9;
        float a = acc2A[o];
        #pragma unroll
        for (int q = 0; q < 9; ++q) a = fmaf(wrow[q], win[q], a);
        acc2A[o] = a;
      }
      #pragma unroll
      for (int dy = 0; dy < 3; ++dy) {
        int r = y1 + dy - 1;
        bool rv = (r >= 0) && (r < 3);
        #pragma unroll
        for (int dx = 0; dx < 3; ++dx) {
          int cc = xx1 + dx - 1;
          bool cv = (cc >= 0) && (cc < 64);
          int tok = r*64 + cc;
          int ph  = (tok & ~31) | ((tok & 31) ^ rot);
          win[dy*3+dx] = (rv && cv) ? Hs[cb + ph] : 0.f;
        }
      }
      #pragma unroll
      for (int o = 0; o < 8; ++o) {
        const float* wrow = ch2w + o*576 + c*9;
        float a = acc2B[o];
        #pragma unroll
        for (int q = 0; q < 9; ++q) a = fmaf(wrow[q], win[q], a);
        acc2B[o] = a;
      }
    }
  }
  #pragma unroll
  for (int o = 0; o < 8; ++o) {
    acc2A[o] += __shfl_xor(acc2A[o], 16); acc2A[o] += __shfl_xor(acc2A[o], 32);
    acc2B[o] += __shfl_xor(acc2B[o], 16); acc2B[o] += __shfl_xor(acc2B[o], 32);
  }
  if (qg == 0) {
    #pragma unroll
    for (int o = 0; o < 8; ++o) {
      c2out[b*1536 + o*192 + t0] = acc2A[o];
      c2out[b*1536 + o*192 + t1] = acc2B[o];
    }
  }
}

// ---------------- K2: fc1 GEMM  z1[4096][768] = relu(c2[4096][1536] @ w2^T + b2) ----------------
// 256 threads, tile 128m x 64n x 32k, 8x4 per thread (rows strided by 16 for bank-conflict-free reads)
__launch_bounds__(256, 4)
__global__ void k2_fc1(const float* __restrict__ A, const float* __restrict__ w2,
                       const float* __restrict__ b2, float* __restrict__ z1) {
  __shared__ float As[128 * 33];
  __shared__ float Bs[32 * 68];
  const int tid = threadIdx.x;
  const int m0 = blockIdx.x * 128;
  const int n0 = blockIdx.y * 64;
  const int tm = tid & 15, tn = tid >> 4;   // tn 0..15

  float acc[8][4];
  #pragma unroll
  for (int i = 0; i < 8; ++i)
    #pragma unroll
    for (int j = 0; j < 4; ++j) acc[i][j] = 0.f;

  for (int k0 = 0; k0 < 1536; k0 += 32) {
    #pragma unroll
    for (int i = 0; i < 4; ++i) {   // stage A 128x32
      int j = tid + i*256;
      int mm = j >> 3, k4 = (j & 7) << 2;
      float4 v = *(const float4*)&A[(m0+mm)*1536 + k0 + k4];
      As[mm*33 + k4+0] = v.x; As[mm*33 + k4+1] = v.y;
      As[mm*33 + k4+2] = v.z; As[mm*33 + k4+3] = v.w;
    }
    #pragma unroll
    for (int i = 0; i < 2; ++i) {   // stage B 64x32 transposed -> Bs[k][68]
      int j = tid + i*256;
      int nn = j >> 3, k4 = (j & 7) << 2;
      float4 v = *(const float4*)&w2[(n0+nn)*1536 + k0 + k4];
      Bs[(k4+0)*68 + nn] = v.x; Bs[(k4+1)*68 + nn] = v.y;
      Bs[(k4+2)*68 + nn] = v.z; Bs[(k4+3)*68 + nn] = v.w;
    }
    __syncthreads();
    #pragma unroll
    for (int k = 0; k < 32; ++k) {
      float a[8];
      #pragma unroll
      for (int i = 0; i < 8; ++i) a[i] = As[(tm + 16*i)*33 + k];
      float4 bv = *(const float4*)&Bs[k*68 + tn*4];
      #pragma unroll
      for (int i = 0; i < 8; ++i) {
        acc[i][0] = fmaf(a[i], bv.x, acc[i][0]);
        acc[i][1] = fmaf(a[i], bv.y, acc[i][1]);
        acc[i][2] = fmaf(a[i], bv.z, acc[i][2]);
        acc[i][3] = fmaf(a[i], bv.w, acc[i][3]);
      }
    }
    __syncthreads();
  }
  float4 bb = *(const float4*)&b2[n0 + tn*4];
  #pragma unroll
  for (int i = 0; i < 8; ++i) {
    float4 r;
    r.x = fmaxf(acc[i][0] + bb.x, 0.f);
    r.y = fmaxf(acc[i][1] + bb.y, 0.f);
    r.z = fmaxf(acc[i][2] + bb.z, 0.f);
    r.w = fmaxf(acc[i][3] + bb.w, 0.f);
    *(float4*)&z1[(m0 + tm + 16*i)*768 + n0 + tn*4] = r;
  }
}

// ---------------- K3: fc2+relu+fc3  out[b] = b4 + sum_o w4[o]*relu(b3[o] + w3[o].z1[b]) ----------------
// 16 samples per block, 256 blocks
__launch_bounds__(256, 2)
__global__ void k3_fc23(const float* __restrict__ z1, const float* __restrict__ w3,
                        const float* __restrict__ b3, const float* __restrict__ w4,
                        const float* __restrict__ b4, float* __restrict__ out) {
  __shared__ float Zs[16 * 772];
  __shared__ float Ws[32 * 68];
  __shared__ float red[256];
  const int tid = threadIdx.x;
  const int m0 = blockIdx.x * 16;
  const int tm = tid & 15, tn = tid >> 4;   // tn 0..15 -> 4 fc2 outputs each

  #pragma unroll
  for (int i = 0; i < 12; ++i) {   // stage Zs 16x768
    int j = tid + i*256;
    int mm = j / 192;
    int kq = j - mm*192;
    float4 v = *(const float4*)&z1[(m0+mm)*768 + kq*4];
    *(float4*)&Zs[mm*772 + kq*4] = v;
  }

  float a0 = 0.f, a1 = 0.f, a2 = 0.f, a3 = 0.f;
  for (int k0 = 0; k0 < 768; k0 += 32) {
    __syncthreads();
    #pragma unroll
    for (int i = 0; i < 2; ++i) {  // stage Ws[32k][68] transposed from w3[n][k]
      int j = tid + i*256;
      int nn = j >> 3, k4 = (j & 7) << 2;
      float4 v = *(const float4*)&w3[nn*768 + k0 + k4];
      Ws[(k4+0)*68 + nn] = v.x; Ws[(k4+1)*68 + nn] = v.y;
      Ws[(k4+2)*68 + nn] = v.z; Ws[(k4+3)*68 + nn] = v.w;
    }
    __syncthreads();
    #pragma unroll
    for (int k = 0; k < 32; k += 4) {
      float4 z  = *(const float4*)&Zs[tm*772 + k0 + k];
      float4 w0 = *(const float4*)&Ws[(k+0)*68 + tn*4];
      float4 w1v= *(const float4*)&Ws[(k+1)*68 + tn*4];
      float4 w2v= *(const float4*)&Ws[(k+2)*68 + tn*4];
      float4 w3v= *(const float4*)&Ws[(k+3)*68 + tn*4];
      a0 = fmaf(z.x, w0.x, a0); a1 = fmaf(z.x, w0.y, a1); a2 = fmaf(z.x, w0.z, a2); a3 = fmaf(z.x, w0.w, a3);
      a0 = fmaf(z.y, w1v.x, a0); a1 = fmaf(z.y, w1v.y, a1); a2 = fmaf(z.y, w1v.z, a2); a3 = fmaf(z.y, w1v.w, a3);
      a0 = fmaf(z.z, w2v.x, a0); a1 = fmaf(z.z, w2v.y, a1); a2 = fmaf(z.z, w2v.z, a2); a3 = fmaf(z.z, w2v.w, a3);
      a0 = fmaf(z.w, w3v.x, a0); a1 = fmaf(z.w, w3v.y, a1); a2 = fmaf(z.w, w3v.z, a2); a3 = fmaf(z.w, w3v.w, a3);
    }
  }
  float4 b3v = *(const float4*)&b3[tn*4];
  float4 w4v = *(const float4*)&w4[tn*4];
  float p = fmaxf(a0 + b3v.x, 0.f) * w4v.x
          + fmaxf(a1 + b3v.y, 0.f) * w4v.y
          + fmaxf(a2 + b3v.z, 0.f) * w4v.z
          + fmaxf(a3 + b3v.w, 0.f) * w4v.w;
  red[tid] = p;
  __syncthreads();
  if (tid < 16) {
    float s = 0.f;
    #pragma unroll
    for (int i = 0; i < 16; ++i) s += red[i*16 + tid];
    out[m0 + tid] = s + b4[0];
  }
}

extern "C" void kernel_launch(void* const* d_in, const int* in_sizes, int n_in,
                              void* d_out, int out_size, void* d_ws, size_t ws_size,
                              hipStream_t stream) {
  const float* x    = (const float*)d_in[0];
  const float* w1   = (const float*)d_in[1];
  const float* b1   = (const float*)d_in[2];
  const float* chw  = (const float*)d_in[3];
  const float* chb  = (const float*)d_in[4];
  const float* gnw  = (const float*)d_in[5];
  const float* gnb  = (const float*)d_in[6];
  const float* wq   = (const float*)d_in[7];
  const float* bq   = (const float*)d_in[8];
  const float* wk   = (const float*)d_in[9];
  const float* bk   = (const float*)d_in[10];
  const float* wv   = (const float*)d_in[11];
  const float* bv   = (const float*)d_in[12];
  const float* wp   = (const float*)d_in[13];
  const float* bp   = (const float*)d_in[14];
  const float* ch2w = (const float*)d_in[15];
  const float* ch2b = (const float*)d_in[16];
  const float* w2   = (const float*)d_in[17];
  const float* b2   = (const float*)d_in[18];
  const float* w3   = (const float*)d_in[19];
  const float* b3   = (const float*)d_in[20];
  const float* w4   = (const float*)d_in[21];
  const float* b4   = (const float*)d_in[22];
  (void)bk; (void)in_sizes; (void)n_in; (void)out_size; (void)ws_size;

  float* ws = (float*)d_ws;
  float* c2 = ws + WS_C2;
  float* z1 = ws + WS_Z1;
  float* out = (float*)d_out;

  hipLaunchKernelGGL(k0_precompute, dim3(34), dim3(256), 0, stream,
                     wq, bq, wk, bk, wv, bv, wp, bp, ws);
  hipLaunchKernelGGL(k1_sample, dim3(4096), dim3(384), 0, stream,
                     x, w1, b1, chw, chb, gnw, gnb, ch2w, ch2b, ws, c2);
  hipLaunchKernelGGL(k2_fc1, dim3(32, 12), dim3(256), 0, stream, c2, w2, b2, z1);
  hipLaunchKernelGGL(k3_fc23, dim3(256), dim3(256), 0, stream, z1, w3, b3, w4, b4, out);
}